// Round 1
// baseline (3018.431 us; speedup 1.0000x reference)
//
#include <hip/hip_runtime.h>

#define D_DIM 2048
#define E_NUM 64
#define M_TOK 16384          // B*L = 4*4096
#define BK 32                // k per staged tile
#define XS_ROW 33            // 32 + 1 pad: bank = (t + kk) % 32 -> 2 lanes/bank (free)
#define XS_TILE (64 * XS_ROW)   // 2112 floats per (half, buf)

// ws layout: gprob[64], gcnt[64], Wt[2048*64] (f32, [k][e])

__global__ __launch_bounds__(128) void init_kernel(float* __restrict__ g) {
    g[threadIdx.x] = 0.0f;   // zeroes gprob[64] + gcnt[64]
}

// one-off transpose W[e][k] -> Wt[k][e]; coalesced reads, scattered 4B writes (tiny)
__global__ __launch_bounds__(256) void wt_kernel(const float* __restrict__ W,
                                                 float* __restrict__ Wt) {
    const int i4 = blockIdx.x * 256 + threadIdx.x;   // grid 128 -> 32768 float4s
    const int e  = i4 >> 9;                          // 0..63
    const int k4 = (i4 & 511) << 2;                  // 0..2044
    const float4 v = *(const float4*)&W[e * D_DIM + k4];
    Wt[(k4 + 0) * E_NUM + e] = v.x;
    Wt[(k4 + 1) * E_NUM + e] = v.y;
    Wt[(k4 + 2) * E_NUM + e] = v.z;
    Wt[(k4 + 3) * E_NUM + e] = v.w;
}

// block = 512 threads = 8 waves; block owns 64 tokens (lane = token).
// wave w: k-half h = w>>2, experts [16*(w&3), +16).
// LDS union (8448 floats):
//   gemm phase: xs(h,buf) at (h*2+buf)*2112, [64 rows][33]
//   epilogue:   S(h) at h*4096 + t*64 + e  (after last loop barrier, xs dead)
//   reduction:  pacc [0..256), cacc [256..512)
__global__ __launch_bounds__(512, 2) void fused_kernel(
    const float* __restrict__ x, const float* __restrict__ Wt,
    float* __restrict__ out, float* __restrict__ gprob, float* __restrict__ gcnt)
{
    __shared__ float lds[4 * XS_TILE];   // 33792 B

    const int tid  = threadIdx.x;
    const int wid  = tid >> 6;
    const int lane = tid & 63;           // token within block
    const int h    = wid >> 2;           // k-half
    const int eb   = (wid & 3) << 4;     // expert base
    const long tok0 = (long)blockIdx.x * 64;
    const int kh   = h << 10;

    // staging role: threads 0..255 stage half 0, 256..511 stage half 1
    const int sh   = tid >> 8;
    const int ss   = tid & 255;
    const int srow = ss >> 2;            // token row 0..63
    const int sc   = (ss & 3) << 2;      // k offset 0,4,8,12
    const float* xsrc = x + (tok0 + srow) * D_DIM + (sh << 10) + sc;

    double accd[16];
    #pragma unroll
    for (int e = 0; e < 16; ++e) accd[e] = 0.0;

    // ---- prologue: stage tile 0 ----
    float4 v0 = *(const float4*)(xsrc);
    float4 v1 = *(const float4*)(xsrc + 16);
    {
        float* d = lds + (sh * 2) * XS_TILE + srow * XS_ROW + sc;
        d[0] = v0.x; d[1] = v0.y; d[2] = v0.z; d[3] = v0.w;
        d[16] = v1.x; d[17] = v1.y; d[18] = v1.z; d[19] = v1.w;
    }
    __syncthreads();

    for (int it = 0; it < 32; ++it) {
        // issue next tile's global loads early (HBM latency hides under compute)
        if (it < 31) {
            const float* p = xsrc + (it + 1) * BK;
            v0 = *(const float4*)(p);
            v1 = *(const float4*)(p + 16);
        }
        // ---- compute tile it from buf (it&1) ----
        const float* xb = lds + (h * 2 + (it & 1)) * XS_TILE + lane * XS_ROW;
        const int kb0 = kh + it * BK;
        #pragma unroll
        for (int c2 = 0; c2 < 2; ++c2) {     // two 16-k chunks (fold granularity)
            float xr[16];
            #pragma unroll
            for (int kk = 0; kk < 16; ++kk) xr[kk] = xb[c2 * 16 + kk];
            float accc[16];
            #pragma unroll
            for (int e = 0; e < 16; ++e) accc[e] = 0.0f;
            const float* wp = Wt + (size_t)(kb0 + c2 * 16) * E_NUM + eb;
            #pragma unroll
            for (int k2 = 0; k2 < 16; ++k2) {    // ascending k, same chunk order as before
                const float4 w0 = *(const float4*)(wp + k2 * E_NUM);
                const float4 w1 = *(const float4*)(wp + k2 * E_NUM + 4);
                const float4 w2 = *(const float4*)(wp + k2 * E_NUM + 8);
                const float4 w3 = *(const float4*)(wp + k2 * E_NUM + 12);
                const float xk = xr[k2];
                accc[0]  += xk * w0.x;  accc[1]  += xk * w0.y;
                accc[2]  += xk * w0.z;  accc[3]  += xk * w0.w;
                accc[4]  += xk * w1.x;  accc[5]  += xk * w1.y;
                accc[6]  += xk * w1.z;  accc[7]  += xk * w1.w;
                accc[8]  += xk * w2.x;  accc[9]  += xk * w2.y;
                accc[10] += xk * w2.z;  accc[11] += xk * w2.w;
                accc[12] += xk * w3.x;  accc[13] += xk * w3.y;
                accc[14] += xk * w3.z;  accc[15] += xk * w3.w;
            }
            #pragma unroll
            for (int e = 0; e < 16; ++e) accd[e] += (double)accc[e];
        }
        // ---- write staged regs into the other buffer ----
        if (it < 31) {
            float* d = lds + (sh * 2 + ((it + 1) & 1)) * XS_TILE + srow * XS_ROW + sc;
            d[0] = v0.x; d[1] = v0.y; d[2] = v0.z; d[3] = v0.w;
            d[16] = v1.x; d[17] = v1.y; d[18] = v1.z; d[19] = v1.w;
        }
        __syncthreads();
    }

    // ---- S overlay: per-half f32 partial logits (same split/cast as before) ----
    {
        float* sp = lds + h * 4096 + lane * 64 + eb;
        *(float4*)(sp + 0)  = make_float4((float)accd[0],  (float)accd[1],
                                          (float)accd[2],  (float)accd[3]);
        *(float4*)(sp + 4)  = make_float4((float)accd[4],  (float)accd[5],
                                          (float)accd[6],  (float)accd[7]);
        *(float4*)(sp + 8)  = make_float4((float)accd[8],  (float)accd[9],
                                          (float)accd[10], (float)accd[11]);
        *(float4*)(sp + 12) = make_float4((float)accd[12], (float)accd[13],
                                          (float)accd[14], (float)accd[15]);
    }
    __syncthreads();

    // ---- fused topk/softmax (h==0 waves; lane = expert; verbatim math) ----
    float pacc = 0.0f, cacc = 0.0f;
    if (h == 0) {
        const int q = wid & 3;
        for (int i = 0; i < 16; ++i) {
            const int  tl = q * 16 + i;
            const long t  = tok0 + tl;
            const float l = lds[tl * 64 + lane] + lds[4096 + tl * 64 + lane];
            // top-1 (max, lowest index on tie — matches jax.lax.top_k)
            float m1 = l; int i1 = lane;
            #pragma unroll
            for (int off = 32; off > 0; off >>= 1) {
                const float ov = __shfl_xor(m1, off, 64);
                const int   oi = __shfl_xor(i1, off, 64);
                if (ov > m1 || (ov == m1 && oi < i1)) { m1 = ov; i1 = oi; }
            }
            // full softmax prob for aux loss
            const float p = __expf(l - m1);
            float s = p;
            #pragma unroll
            for (int off = 32; off > 0; off >>= 1) s += __shfl_xor(s, off, 64);
            pacc += p / s;
            if (lane == i1) cacc += 1.0f;
            // top-2
            const float lm = (lane == i1) ? -1e30f : l;
            float m2 = lm; int i2 = lane;
            #pragma unroll
            for (int off = 32; off > 0; off >>= 1) {
                const float ov = __shfl_xor(m2, off, 64);
                const int   oi = __shfl_xor(i2, off, 64);
                if (ov > m2 || (ov == m2 && oi < i2)) { m2 = ov; i2 = oi; }
            }
            if (lane == 0) {
                out[2 * t]     = (float)i1;
                out[2 * t + 1] = (float)i2;
                const float w1 = 1.0f / (1.0f + __expf(m2 - m1));
                out[2 * M_TOK + 2 * t]     = w1;
                out[2 * M_TOK + 2 * t + 1] = 1.0f - w1;
            }
        }
    }
    __syncthreads();
    if (h == 0) {
        lds[(wid & 3) * 64 + lane]       = pacc;
        lds[256 + (wid & 3) * 64 + lane] = cacc;
    }
    __syncthreads();
    if (wid == 0) {
        // same left-assoc 4-wave combine + one atomic per expert per 64-token block
        atomicAdd(&gprob[lane], lds[lane] + lds[64 + lane] + lds[128 + lane] + lds[192 + lane]);
        atomicAdd(&gcnt[lane],  lds[256 + lane] + lds[320 + lane] + lds[384 + lane] + lds[448 + lane]);
    }
}

__global__ __launch_bounds__(64) void aux_kernel(
    const float* __restrict__ gprob, const float* __restrict__ gcnt,
    float* __restrict__ out)
{
    const int lane = threadIdx.x;
    float v = gprob[lane] * gcnt[lane];
    #pragma unroll
    for (int off = 32; off > 0; off >>= 1) v += __shfl_xor(v, off, 64);
    if (lane == 0)
        out[4 * M_TOK] = 64.0f * 0.01f * v / ((float)M_TOK * (float)M_TOK);
}

extern "C" void kernel_launch(void* const* d_in, const int* in_sizes, int n_in,
                              void* d_out, int out_size, void* d_ws, size_t ws_size,
                              hipStream_t stream)
{
    const float* x = (const float*)d_in[0];
    const float* W = (const float*)d_in[1];
    float* out   = (float*)d_out;
    float* gprob = (float*)d_ws;
    float* gcnt  = gprob + 64;
    float* Wt    = gprob + 128;

    init_kernel<<<1, 128, 0, stream>>>(gprob);
    wt_kernel<<<128, 256, 0, stream>>>(W, Wt);
    fused_kernel<<<256, 512, 0, stream>>>(x, Wt, out, gprob, gcnt);
    aux_kernel<<<1, 64, 0, stream>>>(gprob, gcnt, out);
}

// Round 2
// 2357.529 us; speedup vs baseline: 1.2803x; 1.2803x over previous
//
#include <hip/hip_runtime.h>

#define D_DIM 2048
#define E_NUM 64
#define M_TOK 16384          // B*L = 4*4096
#define BK 32                // k per staged tile
#define XS_ROW 33            // 32 + 1 pad: bank = (t + kk) % 32 -> 2 lanes/bank (free)
#define XS_TILE (64 * XS_ROW)   // 2112 floats per (half, buf)

// ws layout: gprob[64], gcnt[64], Wt[2048*64] (f32, [k][e])

__global__ __launch_bounds__(128) void init_kernel(float* __restrict__ g) {
    g[threadIdx.x] = 0.0f;   // zeroes gprob[64] + gcnt[64]
}

// one-off transpose W[e][k] -> Wt[k][e]; coalesced reads, scattered 4B writes (tiny)
__global__ __launch_bounds__(256) void wt_kernel(const float* __restrict__ W,
                                                 float* __restrict__ Wt) {
    const int i4 = blockIdx.x * 256 + threadIdx.x;   // grid 128 -> 32768 float4s
    const int e  = i4 >> 9;                          // 0..63
    const int k4 = (i4 & 511) << 2;                  // 0..2044
    const float4 v = *(const float4*)&W[e * D_DIM + k4];
    Wt[(k4 + 0) * E_NUM + e] = v.x;
    Wt[(k4 + 1) * E_NUM + e] = v.y;
    Wt[(k4 + 2) * E_NUM + e] = v.z;
    Wt[(k4 + 3) * E_NUM + e] = v.w;
}

// block = 512 threads = 8 waves; block owns 64 tokens (lane = token).
// wave w: k-half h = w>>2, experts [16*(w&3), +16).
// NO min-blocks clause: VGPR cap 256, must not spill (round-1 lesson:
// __launch_bounds__(512,2) forced 128-VGPR cap -> 5.5 GB scratch writes).
// LDS union (8448 floats):
//   gemm phase: xs(h,buf) at (h*2+buf)*2112, [64 rows][33]
//   epilogue:   S(h) at h*4096 + t*64 + e  (after last loop barrier, xs dead)
//   reduction:  pacc [0..256), cacc [256..512)
__global__ __launch_bounds__(512) void fused_kernel(
    const float* __restrict__ x, const float* __restrict__ Wt,
    float* __restrict__ out, float* __restrict__ gprob, float* __restrict__ gcnt)
{
    __shared__ float lds[4 * XS_TILE];   // 33792 B

    const int tid  = threadIdx.x;
    const int wid  = tid >> 6;
    const int lane = tid & 63;           // token within block
    const int h    = wid >> 2;           // k-half
    const int eb   = (wid & 3) << 4;     // expert base
    const long tok0 = (long)blockIdx.x * 64;
    const int kh   = h << 10;

    // staging role: threads 0..255 stage half 0, 256..511 stage half 1
    const int sh   = tid >> 8;
    const int ss   = tid & 255;
    const int srow = ss >> 2;            // token row 0..63
    const int sc   = (ss & 3) << 2;      // k offset 0,4,8,12
    const float* xsrc = x + (tok0 + srow) * D_DIM + (sh << 10) + sc;

    double accd[16];
    #pragma unroll
    for (int e = 0; e < 16; ++e) accd[e] = 0.0;

    // ---- prologue: stage tile 0 ----
    float4 v0 = *(const float4*)(xsrc);
    float4 v1 = *(const float4*)(xsrc + 16);
    {
        float* d = lds + (sh * 2) * XS_TILE + srow * XS_ROW + sc;
        d[0] = v0.x; d[1] = v0.y; d[2] = v0.z; d[3] = v0.w;
        d[16] = v1.x; d[17] = v1.y; d[18] = v1.z; d[19] = v1.w;
    }
    __syncthreads();

    for (int it = 0; it < 32; ++it) {
        // issue next tile's global loads early (HBM latency hides under compute)
        if (it < 31) {
            const float* p = xsrc + (it + 1) * BK;
            v0 = *(const float4*)(p);
            v1 = *(const float4*)(p + 16);
        }
        // ---- compute tile it from buf (it&1) ----
        const float* xb = lds + (h * 2 + (it & 1)) * XS_TILE + lane * XS_ROW;
        const int kb0 = kh + it * BK;
        #pragma unroll
        for (int c2 = 0; c2 < 2; ++c2) {     // two 16-k chunks (fold granularity)
            float xr[16];
            #pragma unroll
            for (int kk = 0; kk < 16; ++kk) xr[kk] = xb[c2 * 16 + kk];
            float accc[16];
            #pragma unroll
            for (int e = 0; e < 16; ++e) accc[e] = 0.0f;
            const float* wp = Wt + (size_t)(kb0 + c2 * 16) * E_NUM + eb;
            // two sequential 8-expert groups: halves live W/accc registers;
            // per-expert k-order (ascending within chunk) unchanged -> same bits
            #pragma unroll
            for (int g = 0; g < 2; ++g) {
                #pragma unroll
                for (int k2 = 0; k2 < 16; ++k2) {
                    const float4 w0 = *(const float4*)(wp + k2 * E_NUM + g * 8);
                    const float4 w1 = *(const float4*)(wp + k2 * E_NUM + g * 8 + 4);
                    const float xk = xr[k2];
                    accc[g * 8 + 0] += xk * w0.x;  accc[g * 8 + 1] += xk * w0.y;
                    accc[g * 8 + 2] += xk * w0.z;  accc[g * 8 + 3] += xk * w0.w;
                    accc[g * 8 + 4] += xk * w1.x;  accc[g * 8 + 5] += xk * w1.y;
                    accc[g * 8 + 6] += xk * w1.z;  accc[g * 8 + 7] += xk * w1.w;
                }
            }
            #pragma unroll
            for (int e = 0; e < 16; ++e) accd[e] += (double)accc[e];
        }
        // ---- write staged regs into the other buffer ----
        if (it < 31) {
            float* d = lds + (sh * 2 + ((it + 1) & 1)) * XS_TILE + srow * XS_ROW + sc;
            d[0] = v0.x; d[1] = v0.y; d[2] = v0.z; d[3] = v0.w;
            d[16] = v1.x; d[17] = v1.y; d[18] = v1.z; d[19] = v1.w;
        }
        __syncthreads();
    }

    // ---- S overlay: per-half f32 partial logits (same split/cast as before) ----
    {
        float* sp = lds + h * 4096 + lane * 64 + eb;
        *(float4*)(sp + 0)  = make_float4((float)accd[0],  (float)accd[1],
                                          (float)accd[2],  (float)accd[3]);
        *(float4*)(sp + 4)  = make_float4((float)accd[4],  (float)accd[5],
                                          (float)accd[6],  (float)accd[7]);
        *(float4*)(sp + 8)  = make_float4((float)accd[8],  (float)accd[9],
                                          (float)accd[10], (float)accd[11]);
        *(float4*)(sp + 12) = make_float4((float)accd[12], (float)accd[13],
                                          (float)accd[14], (float)accd[15]);
    }
    __syncthreads();

    // ---- fused topk/softmax (h==0 waves; lane = expert; verbatim math) ----
    float pacc = 0.0f, cacc = 0.0f;
    if (h == 0) {
        const int q = wid & 3;
        for (int i = 0; i < 16; ++i) {
            const int  tl = q * 16 + i;
            const long t  = tok0 + tl;
            const float l = lds[tl * 64 + lane] + lds[4096 + tl * 64 + lane];
            // top-1 (max, lowest index on tie — matches jax.lax.top_k)
            float m1 = l; int i1 = lane;
            #pragma unroll
            for (int off = 32; off > 0; off >>= 1) {
                const float ov = __shfl_xor(m1, off, 64);
                const int   oi = __shfl_xor(i1, off, 64);
                if (ov > m1 || (ov == m1 && oi < i1)) { m1 = ov; i1 = oi; }
            }
            // full softmax prob for aux loss
            const float p = __expf(l - m1);
            float s = p;
            #pragma unroll
            for (int off = 32; off > 0; off >>= 1) s += __shfl_xor(s, off, 64);
            pacc += p / s;
            if (lane == i1) cacc += 1.0f;
            // top-2
            const float lm = (lane == i1) ? -1e30f : l;
            float m2 = lm; int i2 = lane;
            #pragma unroll
            for (int off = 32; off > 0; off >>= 1) {
                const float ov = __shfl_xor(m2, off, 64);
                const int   oi = __shfl_xor(i2, off, 64);
                if (ov > m2 || (ov == m2 && oi < i2)) { m2 = ov; i2 = oi; }
            }
            if (lane == 0) {
                out[2 * t]     = (float)i1;
                out[2 * t + 1] = (float)i2;
                const float w1 = 1.0f / (1.0f + __expf(m2 - m1));
                out[2 * M_TOK + 2 * t]     = w1;
                out[2 * M_TOK + 2 * t + 1] = 1.0f - w1;
            }
        }
    }
    __syncthreads();
    if (h == 0) {
        lds[(wid & 3) * 64 + lane]       = pacc;
        lds[256 + (wid & 3) * 64 + lane] = cacc;
    }
    __syncthreads();
    if (wid == 0) {
        // same left-assoc 4-wave combine + one atomic per expert per 64-token block
        atomicAdd(&gprob[lane], lds[lane] + lds[64 + lane] + lds[128 + lane] + lds[192 + lane]);
        atomicAdd(&gcnt[lane],  lds[256 + lane] + lds[320 + lane] + lds[384 + lane] + lds[448 + lane]);
    }
}

__global__ __launch_bounds__(64) void aux_kernel(
    const float* __restrict__ gprob, const float* __restrict__ gcnt,
    float* __restrict__ out)
{
    const int lane = threadIdx.x;
    float v = gprob[lane] * gcnt[lane];
    #pragma unroll
    for (int off = 32; off > 0; off >>= 1) v += __shfl_xor(v, off, 64);
    if (lane == 0)
        out[4 * M_TOK] = 64.0f * 0.01f * v / ((float)M_TOK * (float)M_TOK);
}

extern "C" void kernel_launch(void* const* d_in, const int* in_sizes, int n_in,
                              void* d_out, int out_size, void* d_ws, size_t ws_size,
                              hipStream_t stream)
{
    const float* x = (const float*)d_in[0];
    const float* W = (const float*)d_in[1];
    float* out   = (float*)d_out;
    float* gprob = (float*)d_ws;
    float* gcnt  = gprob + 64;
    float* Wt    = gprob + 128;

    init_kernel<<<1, 128, 0, stream>>>(gprob);
    wt_kernel<<<128, 256, 0, stream>>>(W, Wt);
    fused_kernel<<<256, 512, 0, stream>>>(x, Wt, out, gprob, gcnt);
    aux_kernel<<<1, 64, 0, stream>>>(gprob, gcnt, out);
}

// Round 3
// 293.083 us; speedup vs baseline: 10.2989x; 8.0439x over previous
//
#include <hip/hip_runtime.h>

#define D_DIM 2048
#define E_NUM 64
#define M_TOK 16384          // B*L = 4*4096
#define BK 32                // k per staged tile
#define XS_ROW 33            // 32 + 1 pad: bank = (t + kk) % 32 -> 2 lanes/bank (free)
#define XS_TILE (64 * XS_ROW)   // 2112 floats per (half, buf)

// ws layout: gprob[64], gcnt[64], Wt[2048*64] (f32, [k][e])

__global__ __launch_bounds__(128) void init_kernel(float* __restrict__ g) {
    g[threadIdx.x] = 0.0f;   // zeroes gprob[64] + gcnt[64]
}

// one-off transpose W[e][k] -> Wt[k][e]; coalesced reads, scattered 4B writes (tiny)
__global__ __launch_bounds__(256) void wt_kernel(const float* __restrict__ W,
                                                 float* __restrict__ Wt) {
    const int i4 = blockIdx.x * 256 + threadIdx.x;   // grid 128 -> 32768 float4s
    const int e  = i4 >> 9;                          // 0..63
    const int k4 = (i4 & 511) << 2;                  // 0..2044
    const float4 v = *(const float4*)&W[e * D_DIM + k4];
    Wt[(k4 + 0) * E_NUM + e] = v.x;
    Wt[(k4 + 1) * E_NUM + e] = v.y;
    Wt[(k4 + 2) * E_NUM + e] = v.z;
    Wt[(k4 + 3) * E_NUM + e] = v.w;
}

// block = 512 threads = 8 waves; block owns 64 tokens (lane = token).
// wave w: k-half h = w>>2, experts [16*(w&3), +16).
// __launch_bounds__(512, 1): 1 wave/EU min -> 256-VGPR cap (R1/R2 lesson:
// bare (512) and (512,2) both left a 128 cap -> accumulator spill -> 5.5 GB
// scratch traffic). Inner compute is batched 4-k-at-a-time with real loops
// (#pragma unroll 1) so at most 16 W-float4s (64 VGPR) are in flight:
// demand ~146 < 256, no spill even with one-batch lookahead.
// LDS union (8448 floats):
//   gemm phase: xs(h,buf) at (h*2+buf)*2112, [64 rows][33]
//   epilogue:   S(h) at h*4096 + t*64 + e  (after last loop barrier, xs dead)
//   reduction:  pacc [0..256), cacc [256..512)
__global__ __launch_bounds__(512, 1) void fused_kernel(
    const float* __restrict__ x, const float* __restrict__ Wt,
    float* __restrict__ out, float* __restrict__ gprob, float* __restrict__ gcnt)
{
    __shared__ float lds[4 * XS_TILE];   // 33792 B

    const int tid  = threadIdx.x;
    const int wid  = tid >> 6;
    const int lane = tid & 63;           // token within block
    const int h    = wid >> 2;           // k-half
    const int eb   = (wid & 3) << 4;     // expert base
    const long tok0 = (long)blockIdx.x * 64;
    // wave-uniform W offsets via readfirstlane: lets the compiler prove the
    // W addresses uniform (scalar-load eligible); values identical per wave.
    const int ku = __builtin_amdgcn_readfirstlane((wid >> 2) << 10);
    const int eu = __builtin_amdgcn_readfirstlane((wid & 3) << 4);

    // staging role: threads 0..255 stage half 0, 256..511 stage half 1
    const int sh   = tid >> 8;
    const int ss   = tid & 255;
    const int srow = ss >> 2;            // token row 0..63
    const int sc   = (ss & 3) << 2;      // k offset 0,4,8,12
    const float* xsrc = x + (tok0 + srow) * D_DIM + (sh << 10) + sc;

    double accd[16];
    #pragma unroll
    for (int e = 0; e < 16; ++e) accd[e] = 0.0;

    // ---- prologue: stage tile 0 ----
    float4 v0 = *(const float4*)(xsrc);
    float4 v1 = *(const float4*)(xsrc + 16);
    {
        float* d = lds + (sh * 2) * XS_TILE + srow * XS_ROW + sc;
        d[0] = v0.x; d[1] = v0.y; d[2] = v0.z; d[3] = v0.w;
        d[16] = v1.x; d[17] = v1.y; d[18] = v1.z; d[19] = v1.w;
    }
    __syncthreads();

    for (int it = 0; it < 32; ++it) {
        // issue next tile's global loads early (HBM latency hides under compute)
        if (it < 31) {
            const float* p = xsrc + (it + 1) * BK;
            v0 = *(const float4*)(p);
            v1 = *(const float4*)(p + 16);
        }
        // ---- compute tile it from buf (it&1) ----
        const float* xb = lds + (h * 2 + (it & 1)) * XS_TILE + lane * XS_ROW;
        const int kb0 = ku + it * BK;
        #pragma unroll 1
        for (int c2 = 0; c2 < 2; ++c2) {     // two 16-k chunks (fold granularity)
            float accc[16];
            #pragma unroll
            for (int e = 0; e < 16; ++e) accc[e] = 0.0f;
            const float* xc = xb + c2 * 16;
            const float* wp = Wt + (size_t)(kb0 + c2 * 16) * E_NUM + eu;
            #pragma unroll 1
            for (int q = 0; q < 4; ++q) {    // 4 k per batch: bounds W in flight
                const float xr[4] = { xc[q * 4 + 0], xc[q * 4 + 1],
                                      xc[q * 4 + 2], xc[q * 4 + 3] };
                float4 w0[4], w1[4], w2[4], w3[4];   // [k2] x 4 expert quads
                #pragma unroll
                for (int k2 = 0; k2 < 4; ++k2) {
                    const float* wr = wp + (q * 4 + k2) * E_NUM;
                    w0[k2] = *(const float4*)(wr + 0);
                    w1[k2] = *(const float4*)(wr + 4);
                    w2[k2] = *(const float4*)(wr + 8);
                    w3[k2] = *(const float4*)(wr + 12);
                }
                // per-expert k ascending: q outer, k2 inner -> k 0..15 in order
                #pragma unroll
                for (int k2 = 0; k2 < 4; ++k2) {
                    const float xk = xr[k2];
                    accc[0]  += xk * w0[k2].x;  accc[1]  += xk * w0[k2].y;
                    accc[2]  += xk * w0[k2].z;  accc[3]  += xk * w0[k2].w;
                    accc[4]  += xk * w1[k2].x;  accc[5]  += xk * w1[k2].y;
                    accc[6]  += xk * w1[k2].z;  accc[7]  += xk * w1[k2].w;
                    accc[8]  += xk * w2[k2].x;  accc[9]  += xk * w2[k2].y;
                    accc[10] += xk * w2[k2].z;  accc[11] += xk * w2[k2].w;
                    accc[12] += xk * w3[k2].x;  accc[13] += xk * w3[k2].y;
                    accc[14] += xk * w3[k2].z;  accc[15] += xk * w3[k2].w;
                }
            }
            #pragma unroll
            for (int e = 0; e < 16; ++e) accd[e] += (double)accc[e];
        }
        // ---- write staged regs into the other buffer ----
        if (it < 31) {
            float* d = lds + (sh * 2 + ((it + 1) & 1)) * XS_TILE + srow * XS_ROW + sc;
            d[0] = v0.x; d[1] = v0.y; d[2] = v0.z; d[3] = v0.w;
            d[16] = v1.x; d[17] = v1.y; d[18] = v1.z; d[19] = v1.w;
        }
        __syncthreads();
    }

    // ---- S overlay: per-half f32 partial logits (same split/cast as before) ----
    {
        float* sp = lds + h * 4096 + lane * 64 + eb;
        *(float4*)(sp + 0)  = make_float4((float)accd[0],  (float)accd[1],
                                          (float)accd[2],  (float)accd[3]);
        *(float4*)(sp + 4)  = make_float4((float)accd[4],  (float)accd[5],
                                          (float)accd[6],  (float)accd[7]);
        *(float4*)(sp + 8)  = make_float4((float)accd[8],  (float)accd[9],
                                          (float)accd[10], (float)accd[11]);
        *(float4*)(sp + 12) = make_float4((float)accd[12], (float)accd[13],
                                          (float)accd[14], (float)accd[15]);
    }
    __syncthreads();

    // ---- fused topk/softmax (h==0 waves; lane = expert; verbatim math) ----
    float pacc = 0.0f, cacc = 0.0f;
    if (h == 0) {
        const int q = wid & 3;
        for (int i = 0; i < 16; ++i) {
            const int  tl = q * 16 + i;
            const long t  = tok0 + tl;
            const float l = lds[tl * 64 + lane] + lds[4096 + tl * 64 + lane];
            // top-1 (max, lowest index on tie — matches jax.lax.top_k)
            float m1 = l; int i1 = lane;
            #pragma unroll
            for (int off = 32; off > 0; off >>= 1) {
                const float ov = __shfl_xor(m1, off, 64);
                const int   oi = __shfl_xor(i1, off, 64);
                if (ov > m1 || (ov == m1 && oi < i1)) { m1 = ov; i1 = oi; }
            }
            // full softmax prob for aux loss
            const float p = __expf(l - m1);
            float s = p;
            #pragma unroll
            for (int off = 32; off > 0; off >>= 1) s += __shfl_xor(s, off, 64);
            pacc += p / s;
            if (lane == i1) cacc += 1.0f;
            // top-2
            const float lm = (lane == i1) ? -1e30f : l;
            float m2 = lm; int i2 = lane;
            #pragma unroll
            for (int off = 32; off > 0; off >>= 1) {
                const float ov = __shfl_xor(m2, off, 64);
                const int   oi = __shfl_xor(i2, off, 64);
                if (ov > m2 || (ov == m2 && oi < i2)) { m2 = ov; i2 = oi; }
            }
            if (lane == 0) {
                out[2 * t]     = (float)i1;
                out[2 * t + 1] = (float)i2;
                const float w1 = 1.0f / (1.0f + __expf(m2 - m1));
                out[2 * M_TOK + 2 * t]     = w1;
                out[2 * M_TOK + 2 * t + 1] = 1.0f - w1;
            }
        }
    }
    __syncthreads();
    if (h == 0) {
        lds[(wid & 3) * 64 + lane]       = pacc;
        lds[256 + (wid & 3) * 64 + lane] = cacc;
    }
    __syncthreads();
    if (wid == 0) {
        // same left-assoc 4-wave combine + one atomic per expert per 64-token block
        atomicAdd(&gprob[lane], lds[lane] + lds[64 + lane] + lds[128 + lane] + lds[192 + lane]);
        atomicAdd(&gcnt[lane],  lds[256 + lane] + lds[320 + lane] + lds[384 + lane] + lds[448 + lane]);
    }
}

__global__ __launch_bounds__(64) void aux_kernel(
    const float* __restrict__ gprob, const float* __restrict__ gcnt,
    float* __restrict__ out)
{
    const int lane = threadIdx.x;
    float v = gprob[lane] * gcnt[lane];
    #pragma unroll
    for (int off = 32; off > 0; off >>= 1) v += __shfl_xor(v, off, 64);
    if (lane == 0)
        out[4 * M_TOK] = 64.0f * 0.01f * v / ((float)M_TOK * (float)M_TOK);
}

extern "C" void kernel_launch(void* const* d_in, const int* in_sizes, int n_in,
                              void* d_out, int out_size, void* d_ws, size_t ws_size,
                              hipStream_t stream)
{
    const float* x = (const float*)d_in[0];
    const float* W = (const float*)d_in[1];
    float* out   = (float*)d_out;
    float* gprob = (float*)d_ws;
    float* gcnt  = gprob + 64;
    float* Wt    = gprob + 128;

    init_kernel<<<1, 128, 0, stream>>>(gprob);
    wt_kernel<<<128, 256, 0, stream>>>(W, Wt);
    fused_kernel<<<256, 512, 0, stream>>>(x, Wt, out, gprob, gcnt);
    aux_kernel<<<1, 64, 0, stream>>>(gprob, gcnt, out);
}

// Round 4
// 280.947 us; speedup vs baseline: 10.7438x; 1.0432x over previous
//
#include <hip/hip_runtime.h>

#define D_DIM 2048
#define E_NUM 64
#define M_TOK 16384          // B*L = 4*4096
#define BK 32                // k per staged tile
#define XS_ROW 36            // 32 + 4 pad: 144B row stride -> rows 16B-aligned for
                             // ds_read_b128; byte slot 16*(lane%8) = uniform 8x
                             // bank coverage (b128 baseline, no extra conflict)
#define XS_TILE (64 * XS_ROW)   // 2304 floats per (half, buf)

// ws layout: gprob[64], gcnt[64], Wt[2048*64] (f32, [k][e])

// one-off transpose W[e][k] -> Wt[k][e]; block 0 also zeroes gprob/gcnt
__global__ __launch_bounds__(256) void wt_kernel(const float* __restrict__ W,
                                                 float* __restrict__ Wt,
                                                 float* __restrict__ g) {
    if (blockIdx.x == 0 && threadIdx.x < 128) g[threadIdx.x] = 0.0f;
    const int i4 = blockIdx.x * 256 + threadIdx.x;   // grid 128 -> 32768 float4s
    const int e  = i4 >> 9;                          // 0..63
    const int k4 = (i4 & 511) << 2;                  // 0..2044
    const float4 v = *(const float4*)&W[e * D_DIM + k4];
    Wt[(k4 + 0) * E_NUM + e] = v.x;
    Wt[(k4 + 1) * E_NUM + e] = v.y;
    Wt[(k4 + 2) * E_NUM + e] = v.z;
    Wt[(k4 + 3) * E_NUM + e] = v.w;
}

// block = 1024 threads = 16 waves; block owns 64 tokens (lane = token).
// wave w: k-half h = w>>3, experts [8*(w&7), +8).  (R3 lesson: 8 waves = 2
// waves/SIMD could not hide the ~250cyc L2 latency of the Wt loads ->
// VALUBusy 26%. 16 waves = 4/SIMD; per-batch duty 128cyc/(250+128) x4 > 1.)
// __launch_bounds__(1024, 1): 16 waves/CU -> 128-VGPR cap; inner loop bounds
// in-flight W to 16 float4 (+2 x float4) so demand ~110, no spill.
// LDS union (9216 floats):
//   gemm phase: xs(h,buf) at (h*2+buf)*2304, [64 rows][36]
//   epilogue:   S(h) at h*4096 + t*64 + e  (after last loop barrier, xs dead)
//   reduction:  pacc [0..256), cacc [256..512)
__global__ __launch_bounds__(1024, 1) void fused_kernel(
    const float* __restrict__ x, const float* __restrict__ Wt,
    float* __restrict__ out, float* __restrict__ gprob, float* __restrict__ gcnt)
{
    __shared__ float lds[4 * XS_TILE];   // 36864 B

    const int tid  = threadIdx.x;
    const int wid  = tid >> 6;
    const int lane = tid & 63;           // token within block
    const int h    = wid >> 3;           // k-half
    const int eb   = (wid & 7) << 3;     // expert base (8 experts/wave)
    const long tok0 = (long)blockIdx.x * 64;
    // wave-uniform W offsets via readfirstlane (scalar-load eligible)
    const int ku = __builtin_amdgcn_readfirstlane(h << 10);
    const int eu = __builtin_amdgcn_readfirstlane(eb);

    // staging role: threads 0..511 stage half 0, 512..1023 stage half 1;
    // one float4 per thread per tile (64 rows x 32 k per half)
    const int sh   = tid >> 9;
    const int ss   = tid & 511;
    const int srow = ss >> 3;            // token row 0..63
    const int sc   = (ss & 7) << 2;      // k offset 0,4,...,28
    const float* xsrc = x + (tok0 + srow) * D_DIM + (sh << 10) + sc;

    double accd[8];
    #pragma unroll
    for (int e = 0; e < 8; ++e) accd[e] = 0.0;

    // ---- prologue: stage tile 0 ----
    float4 v0 = *(const float4*)(xsrc);
    *(float4*)&lds[(sh * 2) * XS_TILE + srow * XS_ROW + sc] = v0;
    __syncthreads();

    for (int it = 0; it < 32; ++it) {
        // issue next tile's global load early (HBM latency hides under compute)
        if (it < 31) v0 = *(const float4*)(xsrc + (it + 1) * BK);
        // ---- compute tile it from buf (it&1) ----
        const float* xb = lds + (h * 2 + (it & 1)) * XS_TILE + lane * XS_ROW;
        const int kb0 = ku + it * BK;
        #pragma unroll 1
        for (int c2 = 0; c2 < 2; ++c2) {     // two 16-k chunks (fold granularity)
            float accc[8];
            #pragma unroll
            for (int e = 0; e < 8; ++e) accc[e] = 0.0f;
            const float* xc = xb + c2 * 16;
            const float* wp = Wt + (size_t)(kb0 + c2 * 16) * E_NUM + eu;
            #pragma unroll 1
            for (int q = 0; q < 2; ++q) {    // 8-k batches bound W in flight
                const float4 xa = *(const float4*)(xc + q * 8);
                const float4 xs4 = *(const float4*)(xc + q * 8 + 4);
                const float xr[8] = { xa.x, xa.y, xa.z, xa.w,
                                      xs4.x, xs4.y, xs4.z, xs4.w };
                float4 w0[8], w1[8];         // 16 float4 in flight (64 VGPR)
                #pragma unroll
                for (int k2 = 0; k2 < 8; ++k2) {
                    const float* wr = wp + (q * 8 + k2) * E_NUM;
                    w0[k2] = *(const float4*)(wr + 0);
                    w1[k2] = *(const float4*)(wr + 4);
                }
                // per-expert k ascending: q outer, k2 inner -> k 0..15 in order
                #pragma unroll
                for (int k2 = 0; k2 < 8; ++k2) {
                    const float xk = xr[k2];
                    accc[0] += xk * w0[k2].x;  accc[1] += xk * w0[k2].y;
                    accc[2] += xk * w0[k2].z;  accc[3] += xk * w0[k2].w;
                    accc[4] += xk * w1[k2].x;  accc[5] += xk * w1[k2].y;
                    accc[6] += xk * w1[k2].z;  accc[7] += xk * w1[k2].w;
                }
            }
            #pragma unroll
            for (int e = 0; e < 8; ++e) accd[e] += (double)accc[e];
        }
        // ---- write staged reg into the other buffer ----
        if (it < 31)
            *(float4*)&lds[(sh * 2 + ((it + 1) & 1)) * XS_TILE + srow * XS_ROW + sc] = v0;
        __syncthreads();
    }

    // ---- S overlay: per-half f32 partial logits (same split/cast as before) ----
    {
        float* sp = lds + h * 4096 + lane * 64 + eb;
        *(float4*)(sp + 0) = make_float4((float)accd[0], (float)accd[1],
                                         (float)accd[2], (float)accd[3]);
        *(float4*)(sp + 4) = make_float4((float)accd[4], (float)accd[5],
                                         (float)accd[6], (float)accd[7]);
    }
    __syncthreads();

    // ---- fused topk/softmax (waves 0..3; lane = expert; verbatim math) ----
    float pacc = 0.0f, cacc = 0.0f;
    if (wid < 4) {
        const int q = wid;
        for (int i = 0; i < 16; ++i) {
            const int  tl = q * 16 + i;
            const long t  = tok0 + tl;
            const float l = lds[tl * 64 + lane] + lds[4096 + tl * 64 + lane];
            // top-1 (max, lowest index on tie — matches jax.lax.top_k)
            float m1 = l; int i1 = lane;
            #pragma unroll
            for (int off = 32; off > 0; off >>= 1) {
                const float ov = __shfl_xor(m1, off, 64);
                const int   oi = __shfl_xor(i1, off, 64);
                if (ov > m1 || (ov == m1 && oi < i1)) { m1 = ov; i1 = oi; }
            }
            // full softmax prob for aux loss
            const float p = __expf(l - m1);
            float s = p;
            #pragma unroll
            for (int off = 32; off > 0; off >>= 1) s += __shfl_xor(s, off, 64);
            pacc += p / s;
            if (lane == i1) cacc += 1.0f;
            // top-2
            const float lm = (lane == i1) ? -1e30f : l;
            float m2 = lm; int i2 = lane;
            #pragma unroll
            for (int off = 32; off > 0; off >>= 1) {
                const float ov = __shfl_xor(m2, off, 64);
                const int   oi = __shfl_xor(i2, off, 64);
                if (ov > m2 || (ov == m2 && oi < i2)) { m2 = ov; i2 = oi; }
            }
            if (lane == 0) {
                out[2 * t]     = (float)i1;
                out[2 * t + 1] = (float)i2;
                const float w1 = 1.0f / (1.0f + __expf(m2 - m1));
                out[2 * M_TOK + 2 * t]     = w1;
                out[2 * M_TOK + 2 * t + 1] = 1.0f - w1;
            }
        }
    }
    __syncthreads();
    if (wid < 4) {
        lds[wid * 64 + lane]       = pacc;
        lds[256 + wid * 64 + lane] = cacc;
    }
    __syncthreads();
    if (wid == 0) {
        // same left-assoc 4-wave combine + one atomic per expert per 64-token block
        atomicAdd(&gprob[lane], lds[lane] + lds[64 + lane] + lds[128 + lane] + lds[192 + lane]);
        atomicAdd(&gcnt[lane],  lds[256 + lane] + lds[320 + lane] + lds[384 + lane] + lds[448 + lane]);
    }
}

__global__ __launch_bounds__(64) void aux_kernel(
    const float* __restrict__ gprob, const float* __restrict__ gcnt,
    float* __restrict__ out)
{
    const int lane = threadIdx.x;
    float v = gprob[lane] * gcnt[lane];
    #pragma unroll
    for (int off = 32; off > 0; off >>= 1) v += __shfl_xor(v, off, 64);
    if (lane == 0)
        out[4 * M_TOK] = 64.0f * 0.01f * v / ((float)M_TOK * (float)M_TOK);
}

extern "C" void kernel_launch(void* const* d_in, const int* in_sizes, int n_in,
                              void* d_out, int out_size, void* d_ws, size_t ws_size,
                              hipStream_t stream)
{
    const float* x = (const float*)d_in[0];
    const float* W = (const float*)d_in[1];
    float* out   = (float*)d_out;
    float* gprob = (float*)d_ws;
    float* gcnt  = gprob + 64;
    float* Wt    = gprob + 128;

    wt_kernel<<<128, 256, 0, stream>>>(W, Wt, gprob);
    fused_kernel<<<256, 1024, 0, stream>>>(x, Wt, out, gprob, gcnt);
    aux_kernel<<<1, 64, 0, stream>>>(gprob, gcnt, out);
}